// Round 4
// baseline (861.409 us; speedup 1.0000x reference)
//
#include <hip/hip_runtime.h>
#include <hip/hip_bf16.h>

#define NN    50000
#define EE    1600000
#define IND   128
#define OUTD  64
#define SLOPE 0.1f

#define BSH    6                   // log2(nodes per bucket)
#define BW     64                  // nodes per bucket (src >> 6)
#define NB     782                 // ceil(NN / 64)
#define CAP    2560                // bucket capacity: mean 2048 + 11 sigma (fixed input)
#define NBLK   250
#define CHUNK  (EE / NBLK)         // 6400 edges per binscatter block

// ---------------------------------------------------------------------------
// K1: new = x @ W.T + b  (fp32 vector ALU; no fp32 MFMA on CDNA4)
//     nbuf stored as bf16 (row = 128B: halves gather traffic downstream);
//     s_src[n] = new[n].a_src, s_dst[n] = new[n].a_dst kept fp32.
// ---------------------------------------------------------------------------
__global__ __launch_bounds__(256) void linear_kernel(
    const float* __restrict__ x, const float* __restrict__ W,
    const float* __restrict__ bias, const float* __restrict__ a,
    ushort* __restrict__ nbuf2, float* __restrict__ s_src, float* __restrict__ s_dst)
{
    __shared__ float Wt[IND][OUTD + 4];   // Wt[k][j] = W[j*128+k]
    __shared__ float xs[16][IND + 4];
    const int tid = threadIdx.x;

    #pragma unroll
    for (int i = 0; i < 32; ++i) {
        int idx = tid + i * 256;          // coalesced global read of W
        Wt[idx & 127][idx >> 7] = W[idx];
    }
    const int node0 = blockIdx.x * 16;
    const float4* x4 = (const float4*)(x + (size_t)node0 * IND);
    #pragma unroll
    for (int i = 0; i < 2; ++i) {
        int idx = tid + i * 256;          // 512 float4 = 16 rows x 32
        int row = idx >> 5, col = (idx & 31) * 4;
        *(float4*)&xs[row][col] = x4[idx];
    }
    __syncthreads();

    const int nl = tid >> 4;              // local node 0..15
    const int jg = tid & 15;              // dim group
    const int j0 = jg * 4;
    float4 acc = *(const float4*)&bias[j0];
    const float* xrow = xs[nl];
    #pragma unroll
    for (int k = 0; k < IND; k += 4) {
        float4 xv = *(const float4*)&xrow[k];
        float4 w0 = *(const float4*)&Wt[k + 0][j0];
        float4 w1 = *(const float4*)&Wt[k + 1][j0];
        float4 w2 = *(const float4*)&Wt[k + 2][j0];
        float4 w3 = *(const float4*)&Wt[k + 3][j0];
        acc.x = fmaf(xv.x, w0.x, acc.x); acc.y = fmaf(xv.x, w0.y, acc.y);
        acc.z = fmaf(xv.x, w0.z, acc.z); acc.w = fmaf(xv.x, w0.w, acc.w);
        acc.x = fmaf(xv.y, w1.x, acc.x); acc.y = fmaf(xv.y, w1.y, acc.y);
        acc.z = fmaf(xv.y, w1.z, acc.z); acc.w = fmaf(xv.y, w1.w, acc.w);
        acc.x = fmaf(xv.z, w2.x, acc.x); acc.y = fmaf(xv.z, w2.y, acc.y);
        acc.z = fmaf(xv.z, w2.z, acc.z); acc.w = fmaf(xv.z, w2.w, acc.w);
        acc.x = fmaf(xv.w, w3.x, acc.x); acc.y = fmaf(xv.w, w3.y, acc.y);
        acc.z = fmaf(xv.w, w3.z, acc.z); acc.w = fmaf(xv.w, w3.w, acc.w);
    }
    const int n = node0 + nl;
    ushort4 pk;
    { __hip_bfloat16 h;
      h = __float2bfloat16(acc.x); pk.x = *(ushort*)&h;
      h = __float2bfloat16(acc.y); pk.y = *(ushort*)&h;
      h = __float2bfloat16(acc.z); pk.z = *(ushort*)&h;
      h = __float2bfloat16(acc.w); pk.w = *(ushort*)&h; }
    *(ushort4*)&nbuf2[(size_t)n * OUTD + j0] = pk;

    float ss = acc.x * a[j0]        + acc.y * a[j0 + 1]
             + acc.z * a[j0 + 2]    + acc.w * a[j0 + 3];
    float sd = acc.x * a[OUTD + j0]     + acc.y * a[OUTD + j0 + 1]
             + acc.z * a[OUTD + j0 + 2] + acc.w * a[OUTD + j0 + 3];
    #pragma unroll
    for (int m = 1; m < 16; m <<= 1) {
        ss += __shfl_xor(ss, m, 64);
        sd += __shfl_xor(sd, m, 64);
    }
    if (jg == 0) { s_src[n] = ss; s_dst[n] = sd; }
}

// ---------------------------------------------------------------------------
// Binscatter: LDS histogram -> reserve contiguous run in fixed-cap bucket
// region (padded global cursors, no prefix pass) -> packed scatter.
// ---------------------------------------------------------------------------
__global__ __launch_bounds__(256) void binscatter_kernel(const int* __restrict__ ei,
                                                         int* __restrict__ gcur,
                                                         unsigned* __restrict__ ebuf)
{
    __shared__ int h[NB];
    for (int i = threadIdx.x; i < NB; i += 256) h[i] = 0;
    __syncthreads();
    const int base = blockIdx.x * CHUNK;
    const int4* s4p = (const int4*)(ei + base);
    for (int i = threadIdx.x; i < CHUNK / 4; i += 256) {
        int4 s4 = s4p[i];
        atomicAdd(&h[s4.x >> BSH], 1);
        atomicAdd(&h[s4.y >> BSH], 1);
        atomicAdd(&h[s4.z >> BSH], 1);
        atomicAdd(&h[s4.w >> BSH], 1);
    }
    __syncthreads();
    for (int i = threadIdx.x; i < NB; i += 256) {
        int c = h[i];
        if (c) h[i] = i * CAP + atomicAdd(&gcur[i * 16], c);  // padded cursor line
    }
    __syncthreads();
    const int4* d4p = (const int4*)(ei + EE + base);
    for (int i = threadIdx.x; i < CHUNK / 4; i += 256) {
        int4 s4 = s4p[i];
        int4 d4 = d4p[i];
        int p0 = atomicAdd(&h[s4.x >> BSH], 1);
        int p1 = atomicAdd(&h[s4.y >> BSH], 1);
        int p2 = atomicAdd(&h[s4.z >> BSH], 1);
        int p3 = atomicAdd(&h[s4.w >> BSH], 1);
        ebuf[p0] = ((unsigned)(s4.x & (BW - 1)) << 16) | (unsigned)d4.x;
        ebuf[p1] = ((unsigned)(s4.y & (BW - 1)) << 16) | (unsigned)d4.y;
        ebuf[p2] = ((unsigned)(s4.z & (BW - 1)) << 16) | (unsigned)d4.z;
        ebuf[p3] = ((unsigned)(s4.w & (BW - 1)) << 16) | (unsigned)d4.w;
    }
}

// ---------------------------------------------------------------------------
// Fused aggregate: one block per bucket. Edges in arbitrary order; LDS fp32
// atomic accumulation into a 64-node x 64-dim tile (stride 64 -> 2-way bank
// alias = free). bf16 row gathers (128B/edge), 8 in flight per wave.
// ---------------------------------------------------------------------------
__global__ __launch_bounds__(256) void aggregate_kernel(
    const unsigned* __restrict__ ebuf, const int* __restrict__ gcur,
    const ushort* __restrict__ nbuf2,
    const float* __restrict__ s_src, const float* __restrict__ s_dst,
    float* __restrict__ out)
{
    __shared__ float accL[BW * OUTD];   // 16 KB
    __shared__ float esumL[BW];
    __shared__ float ssL[BW];
    const int tid  = threadIdx.x;
    const int wid  = tid >> 6;
    const int lane = tid & 63;
    const int b    = blockIdx.x;
    const int n0   = b << BSH;

    for (int i = tid; i < BW * OUTD; i += 256) accL[i] = 0.f;
    if (tid < BW) {
        esumL[tid] = 0.f;
        int n = n0 + tid;
        ssL[tid] = (n < NN) ? s_src[n] : 0.f;
    }
    __syncthreads();

    const int cnt = gcur[b * 16];
    const unsigned* eb = ebuf + (size_t)b * CAP;

    for (int base = wid * 64; base < cnt; base += 256) {
        const int m = min(64, cnt - base);
        unsigned e = 0; float ev = 0.f;
        if (lane < m) {
            e = eb[base + lane];                  // coalesced packed edge
            int d  = e & 0xFFFFu;
            int ln = e >> 16;
            float sc = ssL[ln] + s_dst[d];        // lane-parallel score+exp
            float lr = sc > 0.f ? sc : SLOPE * sc;
            ev = __expf(lr);
            atomicAdd(&esumL[ln], ev);
        }
        int i = 0;
        for (; i + 8 <= m; i += 8) {
            unsigned e0 = (unsigned)__shfl((int)e, i + 0, 64); float f0 = __shfl(ev, i + 0, 64);
            unsigned e1 = (unsigned)__shfl((int)e, i + 1, 64); float f1 = __shfl(ev, i + 1, 64);
            unsigned e2 = (unsigned)__shfl((int)e, i + 2, 64); float f2 = __shfl(ev, i + 2, 64);
            unsigned e3 = (unsigned)__shfl((int)e, i + 3, 64); float f3 = __shfl(ev, i + 3, 64);
            unsigned e4 = (unsigned)__shfl((int)e, i + 4, 64); float f4 = __shfl(ev, i + 4, 64);
            unsigned e5 = (unsigned)__shfl((int)e, i + 5, 64); float f5 = __shfl(ev, i + 5, 64);
            unsigned e6 = (unsigned)__shfl((int)e, i + 6, 64); float f6 = __shfl(ev, i + 6, 64);
            unsigned e7 = (unsigned)__shfl((int)e, i + 7, 64); float f7 = __shfl(ev, i + 7, 64);
            ushort u0 = nbuf2[(size_t)(e0 & 0xFFFFu) * OUTD + lane];
            ushort u1 = nbuf2[(size_t)(e1 & 0xFFFFu) * OUTD + lane];
            ushort u2 = nbuf2[(size_t)(e2 & 0xFFFFu) * OUTD + lane];
            ushort u3 = nbuf2[(size_t)(e3 & 0xFFFFu) * OUTD + lane];
            ushort u4 = nbuf2[(size_t)(e4 & 0xFFFFu) * OUTD + lane];
            ushort u5 = nbuf2[(size_t)(e5 & 0xFFFFu) * OUTD + lane];
            ushort u6 = nbuf2[(size_t)(e6 & 0xFFFFu) * OUTD + lane];
            ushort u7 = nbuf2[(size_t)(e7 & 0xFFFFu) * OUTD + lane];
            atomicAdd(&accL[(e0 >> 16) * OUTD + lane], f0 * __uint_as_float((unsigned)u0 << 16));
            atomicAdd(&accL[(e1 >> 16) * OUTD + lane], f1 * __uint_as_float((unsigned)u1 << 16));
            atomicAdd(&accL[(e2 >> 16) * OUTD + lane], f2 * __uint_as_float((unsigned)u2 << 16));
            atomicAdd(&accL[(e3 >> 16) * OUTD + lane], f3 * __uint_as_float((unsigned)u3 << 16));
            atomicAdd(&accL[(e4 >> 16) * OUTD + lane], f4 * __uint_as_float((unsigned)u4 << 16));
            atomicAdd(&accL[(e5 >> 16) * OUTD + lane], f5 * __uint_as_float((unsigned)u5 << 16));
            atomicAdd(&accL[(e6 >> 16) * OUTD + lane], f6 * __uint_as_float((unsigned)u6 << 16));
            atomicAdd(&accL[(e7 >> 16) * OUTD + lane], f7 * __uint_as_float((unsigned)u7 << 16));
        }
        for (; i < m; ++i) {
            unsigned ej = (unsigned)__shfl((int)e, i, 64);
            float    fj = __shfl(ev, i, 64);
            ushort   uj = nbuf2[(size_t)(ej & 0xFFFFu) * OUTD + lane];
            atomicAdd(&accL[(ej >> 16) * OUTD + lane], fj * __uint_as_float((unsigned)uj << 16));
        }
    }
    __syncthreads();

    #pragma unroll
    for (int k = 0; k < 16; ++k) {
        int ln = wid * 16 + k;
        int n  = n0 + ln;
        if (n < NN)
            out[(size_t)n * OUTD + lane] = accL[ln * OUTD + lane] / (esumL[ln] + 1e-12f);
    }
}

// ---------------------------------------------------------------------------
extern "C" void kernel_launch(void* const* d_in, const int* in_sizes, int n_in,
                              void* d_out, int out_size, void* d_ws, size_t ws_size,
                              hipStream_t stream) {
    const float* x  = (const float*)d_in[0];
    const int*   ei = (const int*)d_in[1];    // (2,E): [0..E)=src, [E..2E)=dst
    const float* W  = (const float*)d_in[2];
    const float* b  = (const float*)d_in[3];
    const float* a  = (const float*)d_in[4];
    float* out = (float*)d_out;

    // workspace layout (~15 MB)
    ushort*   nbuf2 = (ushort*)d_ws;                      // N*64 bf16 = 6.4 MB
    float*    s_src = (float*)(nbuf2 + (size_t)NN * OUTD);// N
    float*    s_dst = s_src + NN;                         // N
    int*      gcur  = (int*)(s_dst + NN);                 // NB*16 (padded lines)
    unsigned* ebuf  = (unsigned*)(gcur + NB * 16);        // NB*CAP = 8.0 MB

    hipMemsetAsync(gcur, 0, NB * 16 * sizeof(int), stream);
    linear_kernel<<<NN / 16, 256, 0, stream>>>(x, W, b, a, nbuf2, s_src, s_dst);
    binscatter_kernel<<<NBLK, 256, 0, stream>>>(ei, gcur, ebuf);
    aggregate_kernel<<<NB, 256, 0, stream>>>(ebuf, gcur, nbuf2, s_src, s_dst, out);
}

// Round 5
// 190.461 us; speedup vs baseline: 4.5228x; 4.5228x over previous
//
#include <hip/hip_runtime.h>
#include <hip/hip_bf16.h>

#define NN    50000
#define EE    1600000
#define IND   128
#define OUTD  64
#define SLOPE 0.1f

#define BSH    6                   // log2(nodes per bucket)
#define BW     64                  // nodes per bucket (src >> 6)
#define NB     782                 // ceil(NN / 64)
#define CAP    2560                // bucket capacity: mean 2048 + 11 sigma (fixed input)
#define CAPT   10                  // CAP/256: max register-stashed edges per thread
#define NBLK   250
#define CHUNK  (EE / NBLK)         // 6400 edges per binscatter block

// ---------------------------------------------------------------------------
// K1: new = x @ W.T + b  (fp32 vector ALU; no fp32 MFMA on CDNA4)
//     nbuf stored bf16 (row = 128B); s_src/s_dst fp32.
// ---------------------------------------------------------------------------
__global__ __launch_bounds__(256) void linear_kernel(
    const float* __restrict__ x, const float* __restrict__ W,
    const float* __restrict__ bias, const float* __restrict__ a,
    ushort* __restrict__ nbuf2, float* __restrict__ s_src, float* __restrict__ s_dst)
{
    __shared__ float Wt[IND][OUTD + 4];   // Wt[k][j] = W[j*128+k]
    __shared__ float xs[16][IND + 4];
    const int tid = threadIdx.x;

    #pragma unroll
    for (int i = 0; i < 32; ++i) {
        int idx = tid + i * 256;          // coalesced global read of W
        Wt[idx & 127][idx >> 7] = W[idx];
    }
    const int node0 = blockIdx.x * 16;
    const float4* x4 = (const float4*)(x + (size_t)node0 * IND);
    #pragma unroll
    for (int i = 0; i < 2; ++i) {
        int idx = tid + i * 256;          // 512 float4 = 16 rows x 32
        int row = idx >> 5, col = (idx & 31) * 4;
        *(float4*)&xs[row][col] = x4[idx];
    }
    __syncthreads();

    const int nl = tid >> 4;              // local node 0..15
    const int jg = tid & 15;              // dim group
    const int j0 = jg * 4;
    float4 acc = *(const float4*)&bias[j0];
    const float* xrow = xs[nl];
    #pragma unroll
    for (int k = 0; k < IND; k += 4) {
        float4 xv = *(const float4*)&xrow[k];
        float4 w0 = *(const float4*)&Wt[k + 0][j0];
        float4 w1 = *(const float4*)&Wt[k + 1][j0];
        float4 w2 = *(const float4*)&Wt[k + 2][j0];
        float4 w3 = *(const float4*)&Wt[k + 3][j0];
        acc.x = fmaf(xv.x, w0.x, acc.x); acc.y = fmaf(xv.x, w0.y, acc.y);
        acc.z = fmaf(xv.x, w0.z, acc.z); acc.w = fmaf(xv.x, w0.w, acc.w);
        acc.x = fmaf(xv.y, w1.x, acc.x); acc.y = fmaf(xv.y, w1.y, acc.y);
        acc.z = fmaf(xv.y, w1.z, acc.z); acc.w = fmaf(xv.y, w1.w, acc.w);
        acc.x = fmaf(xv.z, w2.x, acc.x); acc.y = fmaf(xv.z, w2.y, acc.y);
        acc.z = fmaf(xv.z, w2.z, acc.z); acc.w = fmaf(xv.z, w2.w, acc.w);
        acc.x = fmaf(xv.w, w3.x, acc.x); acc.y = fmaf(xv.w, w3.y, acc.y);
        acc.z = fmaf(xv.w, w3.z, acc.z); acc.w = fmaf(xv.w, w3.w, acc.w);
    }
    const int n = node0 + nl;
    ushort4 pk;
    { __hip_bfloat16 h;
      h = __float2bfloat16(acc.x); pk.x = *(ushort*)&h;
      h = __float2bfloat16(acc.y); pk.y = *(ushort*)&h;
      h = __float2bfloat16(acc.z); pk.z = *(ushort*)&h;
      h = __float2bfloat16(acc.w); pk.w = *(ushort*)&h; }
    *(ushort4*)&nbuf2[(size_t)n * OUTD + j0] = pk;

    float ss = acc.x * a[j0]        + acc.y * a[j0 + 1]
             + acc.z * a[j0 + 2]    + acc.w * a[j0 + 3];
    float sd = acc.x * a[OUTD + j0]     + acc.y * a[OUTD + j0 + 1]
             + acc.z * a[OUTD + j0 + 2] + acc.w * a[OUTD + j0 + 3];
    #pragma unroll
    for (int m = 1; m < 16; m <<= 1) {
        ss += __shfl_xor(ss, m, 64);
        sd += __shfl_xor(sd, m, 64);
    }
    if (jg == 0) { s_src[n] = ss; s_dst[n] = sd; }
}

// ---------------------------------------------------------------------------
// Binscatter: LDS histogram -> reserve contiguous run in fixed-cap bucket
// region (padded global cursors, no prefix pass) -> packed scatter.
// ---------------------------------------------------------------------------
__global__ __launch_bounds__(256) void binscatter_kernel(const int* __restrict__ ei,
                                                         int* __restrict__ gcur,
                                                         unsigned* __restrict__ ebuf)
{
    __shared__ int h[NB];
    for (int i = threadIdx.x; i < NB; i += 256) h[i] = 0;
    __syncthreads();
    const int base = blockIdx.x * CHUNK;
    const int4* s4p = (const int4*)(ei + base);
    for (int i = threadIdx.x; i < CHUNK / 4; i += 256) {
        int4 s4 = s4p[i];
        atomicAdd(&h[s4.x >> BSH], 1);
        atomicAdd(&h[s4.y >> BSH], 1);
        atomicAdd(&h[s4.z >> BSH], 1);
        atomicAdd(&h[s4.w >> BSH], 1);
    }
    __syncthreads();
    for (int i = threadIdx.x; i < NB; i += 256) {
        int c = h[i];
        if (c) h[i] = i * CAP + atomicAdd(&gcur[i * 16], c);  // padded cursor line
    }
    __syncthreads();
    const int4* d4p = (const int4*)(ei + EE + base);
    for (int i = threadIdx.x; i < CHUNK / 4; i += 256) {
        int4 s4 = s4p[i];
        int4 d4 = d4p[i];
        int p0 = atomicAdd(&h[s4.x >> BSH], 1);
        int p1 = atomicAdd(&h[s4.y >> BSH], 1);
        int p2 = atomicAdd(&h[s4.z >> BSH], 1);
        int p3 = atomicAdd(&h[s4.w >> BSH], 1);
        ebuf[p0] = ((unsigned)(s4.x & (BW - 1)) << 16) | (unsigned)d4.x;
        ebuf[p1] = ((unsigned)(s4.y & (BW - 1)) << 16) | (unsigned)d4.y;
        ebuf[p2] = ((unsigned)(s4.z & (BW - 1)) << 16) | (unsigned)d4.z;
        ebuf[p3] = ((unsigned)(s4.w & (BW - 1)) << 16) | (unsigned)d4.w;
    }
}

// ---------------------------------------------------------------------------
// Fused aggregate v2: one block per bucket. NO per-element atomics.
//  A) register-stash edges, lane-parallel exp, LDS int histogram (64 ctrs)
//  B) wave-0 prefix scan -> node offsets; LDS scatter of (d,ev) pairs
//     sorted by node (ds_write_b64; int cursor atomics only)
//  C) wave x 16 nodes: lane=dim, broadcast ds_read_b64 pair, 8-deep
//     bf16 row gathers, register fma; esum via strided read + shfl.
// ---------------------------------------------------------------------------
__global__ __launch_bounds__(256) void aggregate_kernel(
    const unsigned* __restrict__ ebuf, const int* __restrict__ gcur,
    const ushort* __restrict__ nbuf2,
    const float* __restrict__ s_src, const float* __restrict__ s_dst,
    float* __restrict__ out)
{
    __shared__ uint2 pairs[CAP];        // {d, bits(ev)} sorted by node: 20 KB
    __shared__ float ssL[BW];
    __shared__ int cntL[BW], ofs[BW], cur[BW];
    const int tid  = threadIdx.x;
    const int wid  = tid >> 6;
    const int lane = tid & 63;
    const int b    = blockIdx.x;
    const int n0   = b << BSH;

    if (tid < BW) {
        int n = n0 + tid;
        ssL[tid]  = (n < NN) ? s_src[n] : 0.f;
        cntL[tid] = 0;
    }
    __syncthreads();

    const int cnt = gcur[b * 16];
    const unsigned* eb = ebuf + (size_t)b * CAP;

    unsigned er[CAPT]; float evr[CAPT];
    int nk = 0;
    for (int i = tid; i < cnt; i += 256) {        // coalesced edge load
        unsigned e = eb[i];
        int d  = e & 0xFFFFu;
        int ln = e >> 16;
        float sc = ssL[ln] + s_dst[d];            // parallel gather + exp
        float lr = sc > 0.f ? sc : SLOPE * sc;
        er[nk] = e; evr[nk] = __expf(lr); ++nk;
        atomicAdd(&cntL[ln], 1);                  // int counter only
    }
    __syncthreads();

    if (wid == 0) {                               // 64-ctr exclusive scan
        int c = (lane < BW) ? cntL[lane] : 0;
        int sc = c;
        #pragma unroll
        for (int m = 1; m < 64; m <<= 1) {
            int v = __shfl_up(sc, m, 64);
            if (lane >= m) sc += v;
        }
        if (lane < BW) { ofs[lane] = sc - c; cur[lane] = sc - c; }
    }
    __syncthreads();

    for (int k = 0; k < nk; ++k) {                // sorted LDS scatter
        int ln = er[k] >> 16;
        int pos = atomicAdd(&cur[ln], 1);
        pairs[pos] = make_uint2(er[k] & 0xFFFFu, __float_as_uint(evr[k]));
    }
    __syncthreads();

    #pragma unroll 1
    for (int t = 0; t < 16; ++t) {                // wave's 16 nodes
        const int ln  = wid * 16 + t;
        const int beg = ofs[ln];
        const int len = cntL[ln];

        float es = 0.f;                           // esum: strided + reduce
        for (int j = lane; j < len; j += 64)
            es += __uint_as_float(pairs[beg + j].y);
        #pragma unroll
        for (int m = 1; m < 64; m <<= 1) es += __shfl_xor(es, m, 64);

        float acc = 0.f;
        int j = 0;
        for (; j + 8 <= len; j += 8) {
            uint2 p0 = pairs[beg + j + 0], p1 = pairs[beg + j + 1];
            uint2 p2 = pairs[beg + j + 2], p3 = pairs[beg + j + 3];
            uint2 p4 = pairs[beg + j + 4], p5 = pairs[beg + j + 5];
            uint2 p6 = pairs[beg + j + 6], p7 = pairs[beg + j + 7];
            ushort u0 = nbuf2[(size_t)p0.x * OUTD + lane];
            ushort u1 = nbuf2[(size_t)p1.x * OUTD + lane];
            ushort u2 = nbuf2[(size_t)p2.x * OUTD + lane];
            ushort u3 = nbuf2[(size_t)p3.x * OUTD + lane];
            ushort u4 = nbuf2[(size_t)p4.x * OUTD + lane];
            ushort u5 = nbuf2[(size_t)p5.x * OUTD + lane];
            ushort u6 = nbuf2[(size_t)p6.x * OUTD + lane];
            ushort u7 = nbuf2[(size_t)p7.x * OUTD + lane];
            acc = fmaf(__uint_as_float(p0.y), __uint_as_float((unsigned)u0 << 16), acc);
            acc = fmaf(__uint_as_float(p1.y), __uint_as_float((unsigned)u1 << 16), acc);
            acc = fmaf(__uint_as_float(p2.y), __uint_as_float((unsigned)u2 << 16), acc);
            acc = fmaf(__uint_as_float(p3.y), __uint_as_float((unsigned)u3 << 16), acc);
            acc = fmaf(__uint_as_float(p4.y), __uint_as_float((unsigned)u4 << 16), acc);
            acc = fmaf(__uint_as_float(p5.y), __uint_as_float((unsigned)u5 << 16), acc);
            acc = fmaf(__uint_as_float(p6.y), __uint_as_float((unsigned)u6 << 16), acc);
            acc = fmaf(__uint_as_float(p7.y), __uint_as_float((unsigned)u7 << 16), acc);
        }
        for (; j < len; ++j) {
            uint2 p = pairs[beg + j];
            ushort u = nbuf2[(size_t)p.x * OUTD + lane];
            acc = fmaf(__uint_as_float(p.y), __uint_as_float((unsigned)u << 16), acc);
        }
        const int n = n0 + ln;
        if (n < NN)
            out[(size_t)n * OUTD + lane] = acc / (es + 1e-12f);
    }
}

// ---------------------------------------------------------------------------
extern "C" void kernel_launch(void* const* d_in, const int* in_sizes, int n_in,
                              void* d_out, int out_size, void* d_ws, size_t ws_size,
                              hipStream_t stream) {
    const float* x  = (const float*)d_in[0];
    const int*   ei = (const int*)d_in[1];    // (2,E): [0..E)=src, [E..2E)=dst
    const float* W  = (const float*)d_in[2];
    const float* b  = (const float*)d_in[3];
    const float* a  = (const float*)d_in[4];
    float* out = (float*)d_out;

    // workspace layout (~15 MB)
    ushort*   nbuf2 = (ushort*)d_ws;                      // N*64 bf16 = 6.4 MB
    float*    s_src = (float*)(nbuf2 + (size_t)NN * OUTD);// N
    float*    s_dst = s_src + NN;                         // N
    int*      gcur  = (int*)(s_dst + NN);                 // NB*16 (padded lines)
    unsigned* ebuf  = (unsigned*)(gcur + NB * 16);        // NB*CAP = 8.0 MB

    hipMemsetAsync(gcur, 0, NB * 16 * sizeof(int), stream);
    linear_kernel<<<NN / 16, 256, 0, stream>>>(x, W, b, a, nbuf2, s_src, s_dst);
    binscatter_kernel<<<NBLK, 256, 0, stream>>>(ei, gcur, ebuf);
    aggregate_kernel<<<NB, 256, 0, stream>>>(ebuf, gcur, nbuf2, s_src, s_dst, out);
}